// Round 3
// baseline (328.191 us; speedup 1.0000x reference)
//
#include <hip/hip_runtime.h>
#include <hip/hip_fp16.h>

constexpr int B = 2, H = 12, S = 2048, D = 64;
constexpr int TQ = 16;            // query rows per block
constexpr int SPAD = 2056;        // halves per score row: 2048 + 8 (keeps 16B align, staggers banks)
constexpr int NBLK_Q = S / TQ;    // 128
constexpr int CMAX = 32;          // candidate cap per row (support is ~11 for N(0,1) scores)
constexpr size_t BHSD = (size_t)B * H * S * D;   // 3,145,728

using f16x8 = _Float16 __attribute__((ext_vector_type(8)));
using f16x4 = _Float16 __attribute__((ext_vector_type(4)));
using f32x4 = float __attribute__((ext_vector_type(4)));

// monotone float<->uint encoding for atomicMax on floats
__device__ __forceinline__ unsigned fenc(float f) {
    unsigned u = __float_as_uint(f);
    return (u & 0x80000000u) ? ~u : (u | 0x80000000u);
}
__device__ __forceinline__ float fdec(unsigned e) {
    return __uint_as_float((e & 0x80000000u) ? (e & 0x7fffffffu) : ~e);
}

// ---------------- pre-pass: K fp32 -> f16 (same [bh][k][d] layout) ----------------
__global__ __launch_bounds__(256)
void cvt_k_kernel(const float* __restrict__ K, _Float16* __restrict__ Kh) {
    const size_t i = ((size_t)blockIdx.x * 256 + threadIdx.x) * 4;
    const float4 x = *reinterpret_cast<const float4*>(K + i);
    f16x4 y;
    y[0] = (_Float16)x.x; y[1] = (_Float16)x.y; y[2] = (_Float16)x.z; y[3] = (_Float16)x.w;
    *reinterpret_cast<f16x4*>(Kh + i) = y;
}

// ---------------- pre-pass: V fp32 [bh][k][d] -> f16 transposed [bh][d][k] -------
__global__ __launch_bounds__(256)
void tr_v_kernel(const float* __restrict__ V, _Float16* __restrict__ Vt) {
    __shared__ alignas(16) _Float16 tl[64][68];
    const int bh = blockIdx.x >> 5;
    const int k0 = (blockIdx.x & 31) * 64;
    const int tid = threadIdx.x;
    const int d4 = tid & 15, kl = tid >> 4;
    const float* Vb = V + (size_t)bh * S * D;
    #pragma unroll
    for (int i = 0; i < 4; ++i) {
        const int k = kl + 16 * i;
        const float4 x = *reinterpret_cast<const float4*>(Vb + (size_t)(k0 + k) * D + d4 * 4);
        f16x4 y;
        y[0] = (_Float16)x.x; y[1] = (_Float16)x.y; y[2] = (_Float16)x.z; y[3] = (_Float16)x.w;
        *reinterpret_cast<f16x4*>(&tl[k][d4 * 4]) = y;
    }
    __syncthreads();
    const int d = tid >> 2;
    _Float16* Vtb = Vt + (size_t)bh * D * S + (size_t)d * S + k0;
    #pragma unroll
    for (int i = 0; i < 2; ++i) {
        const int kloc = ((tid & 3) * 2 + i) * 8;
        f16x8 v;
        #pragma unroll
        for (int j = 0; j < 8; ++j) v[j] = tl[kloc + j][d];
        *reinterpret_cast<f16x8*>(Vtb + kloc) = v;
    }
}

// ---------------- main fused kernel ----------------
template <bool PRE>
__global__ __launch_bounds__(256, 2)
void sparsemax_attn_kernel(const float* __restrict__ Q, const float* __restrict__ K,
                           const float* __restrict__ V, const float* __restrict__ mask,
                           const float* __restrict__ scale, float* __restrict__ out,
                           const _Float16* __restrict__ Kh, const _Float16* __restrict__ Vt)
{
    __shared__ alignas(16) _Float16 s_sh[TQ][SPAD];   // 65792 B scores [q][k]; reused f32 in epilogue
    __shared__ float    cand_s[TQ][CMAX + 1];         // +1 float pad -> per-row bank stagger
    __shared__ unsigned mkey_s[TQ];
    __shared__ int      cnt_s[TQ];
    __shared__ float    tau_s[TQ];

    const int tid  = threadIdx.x;
    const int lane = tid & 63;
    const int w    = tid >> 6;              // wave 0..3
    const int row  = lane & 15;
    const int grp  = lane >> 4;             // 0..3
    const int bh   = blockIdx.x / NBLK_Q;
    const int qt   = blockIdx.x - bh * NBLK_Q;
    const int b    = bh / H;
    const int h    = bh - b * H;
    const int q0   = qt * TQ;

    const size_t bhSD = (size_t)bh * S * D;
    const float* mrow = mask + (size_t)b * S;
    const float  sc   = __expf(scale[h]) * 0.125f;

    if (tid < TQ) { mkey_s[tid] = 0u; cnt_s[tid] = 0; }

    // ---- Q fragments (two K=32 chunks): Q[q0+row][c*32 + grp*8 + j] ----
    f16x8 qa[2];
    {
        const float* qr = Q + bhSD + (size_t)(q0 + row) * D + grp * 8;
        #pragma unroll
        for (int c = 0; c < 2; ++c) {
            const float4 x0 = *reinterpret_cast<const float4*>(qr + c * 32);
            const float4 x1 = *reinterpret_cast<const float4*>(qr + c * 32 + 4);
            qa[c][0] = (_Float16)x0.x; qa[c][1] = (_Float16)x0.y;
            qa[c][2] = (_Float16)x0.z; qa[c][3] = (_Float16)x0.w;
            qa[c][4] = (_Float16)x1.x; qa[c][5] = (_Float16)x1.y;
            qa[c][6] = (_Float16)x1.z; qa[c][7] = (_Float16)x1.w;
        }
    }
    __syncthreads();   // init of mkey/cnt visible before phase-1 atomics

    // ---------------- Phase 1: S^T tiles via mfma(K, Q); track row max ----------------
    // Output D[key = grp*4+reg][q = row]; lane writes 4 consecutive k -> one b64 store.
    float vmax = -3.0e38f;
    for (int t = w * 32; t < w * 32 + 32; ++t) {
        const int key0 = t * 16;
        f16x8 kb0, kb1;
        if constexpr (PRE) {
            const _Float16* kp = Kh + bhSD + (size_t)(key0 + row) * D + grp * 8;
            kb0 = *reinterpret_cast<const f16x8*>(kp);
            kb1 = *reinterpret_cast<const f16x8*>(kp + 32);
        } else {
            const float* kp = K + bhSD + (size_t)(key0 + row) * D + grp * 8;
            #pragma unroll
            for (int c = 0; c < 2; ++c) {
                const float4 x0 = *reinterpret_cast<const float4*>(kp + c * 32);
                const float4 x1 = *reinterpret_cast<const float4*>(kp + c * 32 + 4);
                f16x8& kb = c ? kb1 : kb0;
                kb[0] = (_Float16)x0.x; kb[1] = (_Float16)x0.y;
                kb[2] = (_Float16)x0.z; kb[3] = (_Float16)x0.w;
                kb[4] = (_Float16)x1.x; kb[5] = (_Float16)x1.y;
                kb[6] = (_Float16)x1.z; kb[7] = (_Float16)x1.w;
            }
        }
        f32x4 acc = {0.f, 0.f, 0.f, 0.f};
        acc = __builtin_amdgcn_mfma_f32_16x16x32_f16(kb0, qa[0], acc, 0, 0, 0);
        acc = __builtin_amdgcn_mfma_f32_16x16x32_f16(kb1, qa[1], acc, 0, 0, 0);
        const float4 msk = *reinterpret_cast<const float4*>(mrow + key0 + grp * 4);
        const float ma[4] = { (1.0f - msk.x) * -1.0e9f, (1.0f - msk.y) * -1.0e9f,
                              (1.0f - msk.z) * -1.0e9f, (1.0f - msk.w) * -1.0e9f };
        f16x4 st;
        #pragma unroll
        for (int r = 0; r < 4; ++r) {
            const float v = fmaxf(acc[r] * sc + ma[r], -60000.0f);
            st[r] = (_Float16)v;
            vmax = fmaxf(vmax, v);
        }
        *reinterpret_cast<f16x4*>(&s_sh[row][key0 + grp * 4]) = st;
    }
    // combine the 4 k-groups' maxes (same q=row across grp): masks 16,32
    vmax = fmaxf(vmax, __shfl_xor(vmax, 16));
    vmax = fmaxf(vmax, __shfl_xor(vmax, 32));
    if (lane < 16) atomicMax(&mkey_s[lane], fenc(vmax));
    __syncthreads();   // scores + maxes complete

    // ---------------- Phase 2a: candidate extraction (wave w: rows w*4..w*4+3) ----------
    #pragma unroll
    for (int r = 0; r < 4; ++r) {
        const int q = w * 4 + r;
        const float thr = fdec(mkey_s[q]) - 1.01f;   // tau* >= max-1; margin for f16 rounding
        #pragma unroll
        for (int j = 0; j < 4; ++j) {
            const f16x8 zb = *reinterpret_cast<const f16x8*>(&s_sh[q][j * 512 + lane * 8]);
            #pragma unroll
            for (int e = 0; e < 8; ++e) {
                const float z = (float)zb[e];
                if (z > thr) {
                    const int slot = atomicAdd(&cnt_s[q], 1);
                    if (slot < CMAX) cand_s[q][slot] = z;
                }
            }
        }
    }

    // ---------------- Phase 2b: per-group register Newton (group grp -> row w*4+grp) ----
    {
        const int q = w * 4 + grp;
        const int nc = cnt_s[q];                  // same-wave LDS: in-order, no barrier needed
        const float mr = fdec(mkey_s[q]);
        float tau = mr - 1.0f;
        if (nc <= CMAX) {
            float cd[CMAX];
            #pragma unroll
            for (int j = 0; j < CMAX; ++j)
                cd[j] = (j < nc) ? cand_s[q][j] : -1.0e30f;
            #pragma unroll 1
            for (int it = 0; it < 24; ++it) {
                float s0 = 0.f, s1 = 0.f, s2 = 0.f, s3 = 0.f;
                int c = 0;
                #pragma unroll
                for (int j = 0; j < CMAX; j += 4) {
                    const float d0 = cd[j] - tau, d1 = cd[j+1] - tau;
                    const float d2 = cd[j+2] - tau, d3 = cd[j+3] - tau;
                    s0 += fmaxf(d0, 0.f); s1 += fmaxf(d1, 0.f);
                    s2 += fmaxf(d2, 0.f); s3 += fmaxf(d3, 0.f);
                    c += (d0 > 0.f) + (d1 > 0.f) + (d2 > 0.f) + (d3 > 0.f);
                }
                const float ssum = (s0 + s1) + (s2 + s3);
                const float tn = tau + (ssum - 1.0f) / (float)c;
                if (!(tn > tau)) break;           // support stable -> exact
                tau = tn;
            }
        } else {
            // fallback (pathological rows only): Newton with per-iteration LDS scan
            #pragma unroll 1
            for (int it = 0; it < 64; ++it) {
                float ss = 0.f; int c = 0;
                for (int j = 0; j < S / 16; ++j) {
                    const float z = (float)s_sh[q][j * 16 + row];
                    const float d = z - tau;
                    ss += fmaxf(d, 0.f); c += (d > 0.f);
                }
                #pragma unroll
                for (int off = 1; off < 16; off <<= 1) {
                    ss += __shfl_xor(ss, off);
                    c  += __shfl_xor(c, off);
                }
                const float tn = tau + (ss - 1.0f) / (float)c;
                if (!(tn > tau)) break;
                tau = tn;
            }
        }
        if (row == 0) tau_s[q] = tau;
    }
    __syncthreads();   // taus ready for all waves

    // ---------------- Phase 3: out = P.V (MFMA); relu(z-tau) folded into A-frag ----------
    const float tau_row = tau_s[row];
    f32x4 o[4] = {{0.f,0.f,0.f,0.f},{0.f,0.f,0.f,0.f},{0.f,0.f,0.f,0.f},{0.f,0.f,0.f,0.f}};
    for (int c = w * 16; c < w * 16 + 16; ++c) {
        const int k0 = c * 32;
        const f16x8 zb = *reinterpret_cast<const f16x8*>(&s_sh[row][k0 + grp * 8]);
        f16x8 pa;
        #pragma unroll
        for (int j = 0; j < 8; ++j)
            pa[j] = (_Float16)fmaxf((float)zb[j] - tau_row, 0.0f);
        #pragma unroll
        for (int n = 0; n < 4; ++n) {
            f16x8 vb;
            if constexpr (PRE) {
                vb = *reinterpret_cast<const f16x8*>(
                    Vt + (size_t)bh * D * S + (size_t)(n * 16 + row) * S + k0 + grp * 8);
            } else {
                #pragma unroll
                for (int j = 0; j < 8; ++j)
                    vb[j] = (_Float16)V[bhSD + (size_t)(k0 + grp * 8 + j) * D + n * 16 + row];
            }
            o[n] = __builtin_amdgcn_mfma_f32_16x16x32_f16(pa, vb, o[n], 0, 0, 0);
        }
    }
    __syncthreads();   // scores fully consumed; reuse LDS for f32 reduction

    float* red = reinterpret_cast<float*>(&s_sh[0][0]);   // [4][16][64] f32 = 16 KB
    #pragma unroll
    for (int n = 0; n < 4; ++n)
        #pragma unroll
        for (int r = 0; r < 4; ++r)
            red[(w * 16 + grp * 4 + r) * 64 + n * 16 + row] = o[n][r];
    __syncthreads();

    {
        const int base = tid * 4;              // q = base/64, d = base%64
        float4 s0 = *reinterpret_cast<const float4*>(red + 0 * 1024 + base);
        const float4 s1 = *reinterpret_cast<const float4*>(red + 1 * 1024 + base);
        const float4 s2 = *reinterpret_cast<const float4*>(red + 2 * 1024 + base);
        const float4 s3 = *reinterpret_cast<const float4*>(red + 3 * 1024 + base);
        s0.x += s1.x + s2.x + s3.x;
        s0.y += s1.y + s2.y + s3.y;
        s0.z += s1.z + s2.z + s3.z;
        s0.w += s1.w + s2.w + s3.w;
        *reinterpret_cast<float4*>(out + bhSD + (size_t)q0 * D + base) = s0;
    }
}

extern "C" void kernel_launch(void* const* d_in, const int* in_sizes, int n_in,
                              void* d_out, int out_size, void* d_ws, size_t ws_size,
                              hipStream_t stream) {
    const float* Q     = (const float*)d_in[0];
    const float* K     = (const float*)d_in[1];
    const float* V     = (const float*)d_in[2];
    const float* mask  = (const float*)d_in[3];
    const float* scale = (const float*)d_in[4];
    float* out = (float*)d_out;

    const size_t need = 2 * BHSD * sizeof(_Float16);   // Kh + Vt = 12.6 MB
    if (ws_size >= need) {
        _Float16* Kh = (_Float16*)d_ws;
        _Float16* Vt = Kh + BHSD;
        cvt_k_kernel<<<dim3((unsigned)(BHSD / (256 * 4))), dim3(256), 0, stream>>>(K, Kh);
        tr_v_kernel<<<dim3(B * H * (S / 64)), dim3(256), 0, stream>>>(V, Vt);
        sparsemax_attn_kernel<true><<<dim3(B * H * NBLK_Q), dim3(256), 0, stream>>>(
            Q, K, V, mask, scale, out, Kh, Vt);
    } else {
        sparsemax_attn_kernel<false><<<dim3(B * H * NBLK_Q), dim3(256), 0, stream>>>(
            Q, K, V, mask, scale, out, nullptr, nullptr);
    }
}

// Round 4
// 219.787 us; speedup vs baseline: 1.4932x; 1.4932x over previous
//
#include <hip/hip_runtime.h>
#include <hip/hip_fp16.h>

constexpr int B = 2, H = 12, S = 2048, D = 64;
constexpr int TQ = 16;            // query rows per block
constexpr int PADH = 18;          // halves per LDS score row (16 q + 2 pad -> stride 36B, 2-way-free banks)
constexpr int NBLK_Q = S / TQ;    // 128
constexpr size_t BHSD = (size_t)B * H * S * D;   // 3,145,728

using f16x8 = _Float16 __attribute__((ext_vector_type(8)));
using f16x4 = _Float16 __attribute__((ext_vector_type(4)));
using f32x4 = float __attribute__((ext_vector_type(4)));

// ---------------- pre-pass: K fp32 -> f16 (same [bh][k][d] layout) ----------------
__global__ __launch_bounds__(256)
void cvt_k_kernel(const float* __restrict__ K, _Float16* __restrict__ Kh) {
    const size_t i = ((size_t)blockIdx.x * 256 + threadIdx.x) * 4;
    const float4 x = *reinterpret_cast<const float4*>(K + i);
    f16x4 y;
    y[0] = (_Float16)x.x; y[1] = (_Float16)x.y; y[2] = (_Float16)x.z; y[3] = (_Float16)x.w;
    *reinterpret_cast<f16x4*>(Kh + i) = y;
}

// ---------------- pre-pass: V fp32 [bh][k][d] -> f16 transposed [bh][d][k] -------
__global__ __launch_bounds__(256)
void tr_v_kernel(const float* __restrict__ V, _Float16* __restrict__ Vt) {
    __shared__ alignas(16) _Float16 tl[64][68];
    const int bh = blockIdx.x >> 5;
    const int k0 = (blockIdx.x & 31) * 64;
    const int tid = threadIdx.x;
    const int d4 = tid & 15, kl = tid >> 4;
    const float* Vb = V + (size_t)bh * S * D;
    #pragma unroll
    for (int i = 0; i < 4; ++i) {
        const int k = kl + 16 * i;
        const float4 x = *reinterpret_cast<const float4*>(Vb + (size_t)(k0 + k) * D + d4 * 4);
        f16x4 y;
        y[0] = (_Float16)x.x; y[1] = (_Float16)x.y; y[2] = (_Float16)x.z; y[3] = (_Float16)x.w;
        *reinterpret_cast<f16x4*>(&tl[k][d4 * 4]) = y;
    }
    __syncthreads();
    const int d = tid >> 2;
    _Float16* Vtb = Vt + (size_t)bh * D * S + (size_t)d * S + k0;
    #pragma unroll
    for (int i = 0; i < 2; ++i) {
        const int kloc = ((tid & 3) * 2 + i) * 8;
        f16x8 v;
        #pragma unroll
        for (int j = 0; j < 8; ++j) v[j] = tl[kloc + j][d];
        *reinterpret_cast<f16x8*>(Vtb + kloc) = v;
    }
}

// ---------------- main fused kernel: 1024 threads / 16 waves per block ----------------
template <bool PRE>
__global__ __launch_bounds__(1024, 8)
void sparsemax_attn_kernel(const float* __restrict__ Q, const float* __restrict__ K,
                           const float* __restrict__ V, const float* __restrict__ mask,
                           const float* __restrict__ scale, float* __restrict__ out,
                           const _Float16* __restrict__ Kh, const _Float16* __restrict__ Vt)
{
    __shared__ alignas(16) _Float16 s_sh[S * PADH];   // 73728 B: scores [k][q]; reused f32 red
    __shared__ float tau_s[TQ];

    const int tid  = threadIdx.x;
    const int lane = tid & 63;
    const int w    = tid >> 6;              // wave 0..15
    const int row  = lane & 15;             // frag row/col index
    const int grp  = lane >> 4;             // frag k-group 0..3
    const int bh   = blockIdx.x / NBLK_Q;
    const int qt   = blockIdx.x - bh * NBLK_Q;
    const int b    = bh / H;
    const int h    = bh - b * H;
    const int q0   = qt * TQ;

    const size_t bhSD = (size_t)bh * S * D;
    const float* mrow = mask + (size_t)b * S;
    const float  sc   = __expf(scale[h]) * 0.125f;   // exp(scale)/sqrt(64)

    // ---- Q A-fragments (16 x 64, two K=32 chunks): Q[q0+row][c*32 + grp*8 + j] ----
    f16x8 qa[2];
    {
        const float* qr = Q + bhSD + (size_t)(q0 + row) * D + grp * 8;
        #pragma unroll
        for (int c = 0; c < 2; ++c) {
            const float4 x0 = *reinterpret_cast<const float4*>(qr + c * 32);
            const float4 x1 = *reinterpret_cast<const float4*>(qr + c * 32 + 4);
            qa[c][0] = (_Float16)x0.x; qa[c][1] = (_Float16)x0.y;
            qa[c][2] = (_Float16)x0.z; qa[c][3] = (_Float16)x0.w;
            qa[c][4] = (_Float16)x1.x; qa[c][5] = (_Float16)x1.y;
            qa[c][6] = (_Float16)x1.z; qa[c][7] = (_Float16)x1.w;
        }
    }

    // ---------------- Phase 1: scores = (QK^T)*sc + mask  (MFMA) ----------------
    // wave w handles 16-key tiles t = w*8 .. w*8+7
    for (int t = w * 8; t < w * 8 + 8; ++t) {
        const int key0 = t * 16;
        const int key  = key0 + row;
        f16x8 kb0, kb1;
        if constexpr (PRE) {
            const _Float16* kp = Kh + bhSD + (size_t)key * D + grp * 8;
            kb0 = *reinterpret_cast<const f16x8*>(kp);
            kb1 = *reinterpret_cast<const f16x8*>(kp + 32);
        } else {
            const float* kp = K + bhSD + (size_t)key * D + grp * 8;
            #pragma unroll
            for (int c = 0; c < 2; ++c) {
                const float4 x0 = *reinterpret_cast<const float4*>(kp + c * 32);
                const float4 x1 = *reinterpret_cast<const float4*>(kp + c * 32 + 4);
                f16x8& kb = c ? kb1 : kb0;
                kb[0] = (_Float16)x0.x; kb[1] = (_Float16)x0.y;
                kb[2] = (_Float16)x0.z; kb[3] = (_Float16)x0.w;
                kb[4] = (_Float16)x1.x; kb[5] = (_Float16)x1.y;
                kb[6] = (_Float16)x1.z; kb[7] = (_Float16)x1.w;
            }
        }
        f32x4 acc = {0.f, 0.f, 0.f, 0.f};
        acc = __builtin_amdgcn_mfma_f32_16x16x32_f16(qa[0], kb0, acc, 0, 0, 0);
        acc = __builtin_amdgcn_mfma_f32_16x16x32_f16(qa[1], kb1, acc, 0, 0, 0);
        const float madd = (1.0f - mrow[key]) * -1.0e9f;
        // D mapping: col(=key within tile)=lane&15, row(=q)=grp*4+reg
        #pragma unroll
        for (int r = 0; r < 4; ++r) {
            const float v = fmaxf(acc[r] * sc + madd, -60000.0f);
            s_sh[(size_t)key * PADH + grp * 4 + r] = (_Float16)v;
        }
    }
    __syncthreads();

    // ---------------- Phase 2: exact tau via Newton; wave w owns row q = w ----------------
    {
        const int q = w;
        float z[32];
        #pragma unroll
        for (int j = 0; j < 32; ++j)
            z[j] = (float)s_sh[(size_t)(j * 64 + lane) * PADH + q];
        float m = z[0];
        #pragma unroll
        for (int j = 1; j < 32; ++j) m = fmaxf(m, z[j]);
        #pragma unroll
        for (int off = 32; off >= 1; off >>= 1) m = fmaxf(m, __shfl_xor(m, off));
        float tau = m - 1.0f;                 // f(tau0) >= 0; Newton ascends monotonically
        #pragma unroll 1
        for (int it = 0; it < 32; ++it) {
            float s1 = 0.f;
            int   cnt = 0;
            #pragma unroll
            for (int j = 0; j < 32; ++j) {
                const float dlt = z[j] - tau;
                s1 += fmaxf(dlt, 0.f);
                cnt += (int)__popcll(__ballot(dlt > 0.f));
            }
            #pragma unroll
            for (int off = 32; off >= 1; off >>= 1) s1 += __shfl_xor(s1, off);
            const float tn = tau + (s1 - 1.0f) / (float)cnt;
            if (!(tn > tau)) break;           // support stable -> exact
            tau = tn;
        }
        if (lane == 0) tau_s[q] = tau;
    }
    __syncthreads();

    // ---------------- Phase 3: out = P.V (MFMA); relu(z-tau) folded into A-frag ----------
    const float tau_row = tau_s[row];         // this lane's q for the A fragment
    f32x4 o[4] = {{0.f,0.f,0.f,0.f},{0.f,0.f,0.f,0.f},{0.f,0.f,0.f,0.f},{0.f,0.f,0.f,0.f}};
    for (int c = w * 4; c < w * 4 + 4; ++c) {
        const int k0 = c * 32;
        f16x8 pa;
        #pragma unroll
        for (int j = 0; j < 8; ++j) {
            const float z = (float)s_sh[(size_t)(k0 + grp * 8 + j) * PADH + row];
            pa[j] = (_Float16)fmaxf(z - tau_row, 0.0f);
        }
        #pragma unroll
        for (int n = 0; n < 4; ++n) {
            f16x8 vb;
            if constexpr (PRE) {
                vb = *reinterpret_cast<const f16x8*>(
                    Vt + (size_t)bh * D * S + (size_t)(n * 16 + row) * S + k0 + grp * 8);
            } else {
                #pragma unroll
                for (int j = 0; j < 8; ++j)
                    vb[j] = (_Float16)V[bhSD + (size_t)(k0 + grp * 8 + j) * D + n * 16 + row];
            }
            o[n] = __builtin_amdgcn_mfma_f32_16x16x32_f16(pa, vb, o[n], 0, 0, 0);
        }
    }
    __syncthreads();   // scores fully consumed; reuse LDS for f32 reduction

    // cross-wave reduction: red[16 partials][16 q][64 d] f32 = 64 KB (fits in s_sh)
    float* red = reinterpret_cast<float*>(s_sh);
    #pragma unroll
    for (int n = 0; n < 4; ++n)
        #pragma unroll
        for (int r = 0; r < 4; ++r)
            red[w * 1024 + (grp * 4 + r) * 64 + n * 16 + row] = o[n][r];
    __syncthreads();

    {
        const int q = tid >> 6;               // 0..15
        const int d = tid & 63;               // 0..63
        float sum = 0.f;
        #pragma unroll
        for (int p = 0; p < 16; ++p)
            sum += red[p * 1024 + q * 64 + d];
        out[bhSD + (size_t)(q0 + q) * D + d] = sum;
    }
}

extern "C" void kernel_launch(void* const* d_in, const int* in_sizes, int n_in,
                              void* d_out, int out_size, void* d_ws, size_t ws_size,
                              hipStream_t stream) {
    const float* Q     = (const float*)d_in[0];
    const float* K     = (const float*)d_in[1];
    const float* V     = (const float*)d_in[2];
    const float* mask  = (const float*)d_in[3];
    const float* scale = (const float*)d_in[4];
    float* out = (float*)d_out;

    const size_t need = 2 * BHSD * sizeof(_Float16);   // Kh + Vt = 12.6 MB
    if (ws_size >= need) {
        _Float16* Kh = (_Float16*)d_ws;
        _Float16* Vt = Kh + BHSD;
        cvt_k_kernel<<<dim3((unsigned)(BHSD / (256 * 4))), dim3(256), 0, stream>>>(K, Kh);
        tr_v_kernel<<<dim3(B * H * (S / 64)), dim3(256), 0, stream>>>(V, Vt);
        sparsemax_attn_kernel<true><<<dim3(B * H * NBLK_Q), dim3(1024), 0, stream>>>(
            Q, K, V, mask, scale, out, Kh, Vt);
    } else {
        sparsemax_attn_kernel<false><<<dim3(B * H * NBLK_Q), dim3(1024), 0, stream>>>(
            Q, K, V, mask, scale, out, nullptr, nullptr);
    }
}